// Round 9
// baseline (143.912 us; speedup 1.0000x reference)
//
#include <hip/hip_runtime.h>
#include <stdint.h>

#define A 15
#define H_ 34
#define W_ 34
#define HW (H_*W_)
#define N (A*HW)            // 17340
#define MAX_CAND 3000
#define TOP_N 300
#define NWORDS 47           // ceil(3000/64)
#define CHUNK_W 3008        // 64 rows * 47 words per chunk
#define NBUCK 8000          // linear score buckets (monotone quantization)

__constant__ float c_aw[A] = {9.232984f, 16.0f, 27.712813f, 18.465969f, 32.0f, 55.425626f,
                              36.931937f, 64.0f, 110.851252f, 73.863875f, 128.0f, 221.702503f,
                              147.72775f, 256.0f, 443.405007f};
__constant__ float c_ah[A] = {27.72668f, 16.0f, 9.237604f, 55.453359f, 32.0f, 18.475209f,
                              110.906719f, 64.0f, 36.950417f, 221.813438f, 128.0f, 73.900834f,
                              443.626876f, 256.0f, 147.801669f};

// ---------------------------------------------------------------------------
// K1: decode boxes/scores; key = bucket(13) | score-bits(32) | ~idx(15).
// Exact reference op order; __f*_rn blocks FMA contraction.
// ---------------------------------------------------------------------------
__global__ __launch_bounds__(256) void k_boxes(
    const float* __restrict__ cls, const float* __restrict__ pred,
    const int* __restrict__ iminfo,
    float4* __restrict__ boxes, float2* __restrict__ scores,
    unsigned long long* __restrict__ keys)
{
    int m = blockIdx.x * 256 + threadIdx.x;
    if (m >= N) return;

    int a  = m % A;
    int hw = m / A;
    int w  = hw % W_;
    int h  = hw / W_;

    float ow = (float)iminfo[1];
    float oh = (float)iminfo[0];

    float aw = c_aw[a], ah = c_ah[a];
    float xm = __fmul_rn(-0.5f, __fsub_rn(aw, 1.0f));
    float ym = __fmul_rn(-0.5f, __fsub_rn(ah, 1.0f));
    float sxw = (float)(w * 8);
    float syh = (float)(h * 8);
    float x1 = __fadd_rn(sxw, xm);
    float y1 = __fadd_rn(syh, ym);
    float x2 = __fadd_rn(sxw, -xm);
    float y2 = __fadd_rn(syh, -ym);

    float widths  = __fadd_rn(__fsub_rn(x2, x1), 1.0f);
    float heights = __fadd_rn(__fsub_rn(y2, y1), 1.0f);
    float ctr_x = __fadd_rn(x1, __fmul_rn(0.5f, __fsub_rn(widths, 1.0f)));
    float ctr_y = __fadd_rn(y1, __fmul_rn(0.5f, __fsub_rn(heights, 1.0f)));

    const float std0 = 0.12677f,   std1 = 0.095741f, std2 = 0.3173f,    std3 = 0.281042f;
    const float mu0  = 0.000437f,  mu1  = 0.002586f, mu2  = -0.123953f, mu3  = -0.081469f;
    int pb = a * 4 * HW + hw;
    float d0 = __fadd_rn(__fmul_rn(pred[pb + 0 * HW], std0), mu0);
    float d1 = __fadd_rn(__fmul_rn(pred[pb + 1 * HW], std1), mu1);
    float d2 = __fadd_rn(__fmul_rn(pred[pb + 2 * HW], std2), mu2);
    float d3 = __fadd_rn(__fmul_rn(pred[pb + 3 * HW], std3), mu3);

    float pcx = __fadd_rn(__fmul_rn(d0, widths),  ctr_x);
    float pcy = __fadd_rn(__fmul_rn(d1, heights), ctr_y);
    float pw  = __fmul_rn(expf(d2), widths);
    float ph  = __fmul_rn(expf(d3), heights);

    float hpw = __fmul_rn(0.5f, __fsub_rn(pw, 1.0f));
    float hph = __fmul_rn(0.5f, __fsub_rn(ph, 1.0f));
    float bx1 = __fsub_rn(pcx, hpw);
    float by1 = __fsub_rn(pcy, hph);
    float bx2 = __fadd_rn(pcx, hpw);
    float by2 = __fadd_rn(pcy, hph);

    float ow1 = __fsub_rn(ow, 1.0f), oh1 = __fsub_rn(oh, 1.0f);
    bx1 = fminf(fmaxf(bx1, 0.0f), ow1);
    by1 = fminf(fmaxf(by1, 0.0f), oh1);
    bx2 = fminf(fmaxf(bx2, 0.0f), ow1);
    by2 = fminf(fmaxf(by2, 0.0f), oh1);

    float s0 = cls[a * HW + hw];
    float s1 = cls[(A + a) * HW + hw];

    float wsv = __fadd_rn(__fsub_rn(bx2, bx1), 1.0f);
    float hsv = __fadd_rn(__fsub_rn(by2, by1), 1.0f);
    bool keep = (s1 > 0.2f) && ((wsv >= 6.16056f) || (hsv >= 6.16056f));
    float masked = keep ? s1 : -1e30f;

    boxes[m]  = make_float4(bx1, by1, bx2, by2);
    scores[m] = make_float2(s0, s1);

    int bucket = keep ? (1 + min(NBUCK - 2, max(0, (int)(s1 * (float)(NBUCK - 2))))) : 0;
    unsigned int fb = __float_as_uint(masked);
    fb = (fb & 0x80000000u) ? ~fb : (fb | 0x80000000u);
    keys[m] = ((unsigned long long)bucket << 51)
            | ((unsigned long long)fb << 15)
            | (unsigned long long)((~m) & 0x7fff);
}

// ---------------------------------------------------------------------------
// K2: single block, 1024 threads. LDS histogram over 8000 buckets ->
// suffix scan -> threshold bucket B -> bucket-grouped compact -> rank =
// base[b] + tiny within-bucket compare -> scatter. (verified R8)
// ---------------------------------------------------------------------------
__global__ __launch_bounds__(1024) void k_mid(
    const unsigned long long* __restrict__ keys,
    const float4* __restrict__ boxes, const float2* __restrict__ scores,
    unsigned long long* __restrict__ skeys,
    float4* __restrict__ cboxes, float2* __restrict__ cscores,
    unsigned long long* __restrict__ kpm)
{
    __shared__ int s_base[NBUCK];               // counts -> suffix bases
    __shared__ int s_off[NBUCK];                // tsum alias, then bucket offsets
    __shared__ unsigned long long s_kpm[NWORDS];
    __shared__ int s_B[1];

    const int t = threadIdx.x;

    for (int k = t; k < NBUCK; k += 1024) s_base[k] = 0;
    if (t < NWORDS) s_kpm[t] = 0ull;
    __syncthreads();

    unsigned long long myk[17];
    #pragma unroll
    for (int q = 0; q < 17; ++q) {
        int i = q * 1024 + t;
        myk[q] = (i < N) ? keys[i] : 0ull;
        if (i < N) atomicAdd(&s_base[(int)(myk[q] >> 51)], 1);
    }
    __syncthreads();

    int c0=0,c1=0,c2=0,c3=0,c4=0,c5=0,c6=0,c7=0;
    int gsum = 0;
    const int g0 = t * 8;
    if (t < NBUCK / 8) {
        c0 = s_base[g0+0]; c1 = s_base[g0+1]; c2 = s_base[g0+2]; c3 = s_base[g0+3];
        c4 = s_base[g0+4]; c5 = s_base[g0+5]; c6 = s_base[g0+6]; c7 = s_base[g0+7];
        gsum = c0+c1+c2+c3+c4+c5+c6+c7;
    }
    int* tsum = s_off;
    tsum[t] = gsum;
    __syncthreads();
    for (int d = 1; d < 1024; d <<= 1) {
        int v = (t + d < 1024) ? tsum[t + d] : 0;
        __syncthreads();
        tsum[t] += v;
        __syncthreads();
    }
    int above = (t < 1023) ? tsum[t + 1] : 0;

    if (t < NBUCK / 8) {
        int run = above;
        #define STEP(q, cq) { s_base[g0+q] = run; \
            if (run < MAX_CAND && run + cq >= MAX_CAND) s_B[0] = g0 + q; \
            run += cq; }
        STEP(7, c7) STEP(6, c6) STEP(5, c5) STEP(4, c4)
        STEP(3, c3) STEP(2, c2) STEP(1, c1) STEP(0, c0)
        #undef STEP
    }
    __syncthreads();
    const int B = s_B[0];
    for (int k = t; k < NBUCK; k += 1024) s_off[k] = 0;
    __syncthreads();

    #pragma unroll
    for (int q = 0; q < 17; ++q) {
        int i = q * 1024 + t;
        if (i < N) {
            int b = (int)(myk[q] >> 51);
            if (b >= B) {
                int slot = s_base[b] + atomicAdd(&s_off[b], 1);
                skeys[slot] = myk[q];
            }
        }
    }
    __syncthreads();
    const int S = s_base[B] + s_off[B];

    for (int p = t; p < S; p += 1024) {
        unsigned long long k = skeys[p];
        int b  = (int)(k >> 51);
        int lo = s_base[b];
        int hi = lo + s_off[b];
        int cg = 0;
        for (int j = lo; j < hi; ++j) cg += (skeys[j] > k) ? 1 : 0;
        int rank = lo + cg;
        if (rank < MAX_CAND) {
            int orig = ((int)k & 0x7fff) ^ 0x7fff;
            cboxes[rank]  = boxes[orig];
            cscores[rank] = scores[orig];
            if (b >= 1) atomicOr(&s_kpm[rank >> 6], 1ull << (rank & 63));
        }
    }
    __syncthreads();
    if (t < NWORDS) kpm[t] = s_kpm[t];
}

// ---------------------------------------------------------------------------
// K3: suppression bitmask, register-blocked + triangular.
// Block bid = chunk bid (rows 64*bid..64*bid+63), 16 waves x 4 rows/wave.
// Per word w (starting at bid -- words < bid are never read downstream):
// one LDS read of bj per lane serves 4 rows held in registers.
// ---------------------------------------------------------------------------
__device__ __forceinline__ bool iou_gt(
    float4 bi, float ai, float4 bj, float aj)
{
    float iw = fmaxf(__fsub_rn(fminf(bi.z, bj.z), fmaxf(bi.x, bj.x)), 0.0f);
    float ih = fmaxf(__fsub_rn(fminf(bi.w, bj.w), fmaxf(bi.y, bj.y)), 0.0f);
    float inter = __fmul_rn(iw, ih);
    float denom = fmaxf(__fsub_rn(__fadd_rn(ai, aj), inter), 1e-12f);
    return (inter / denom) > 0.7f;
}

__global__ __launch_bounds__(1024) void k_iou(
    const float4* __restrict__ cboxes, unsigned long long* __restrict__ sup)
{
    __shared__ float4 bx[MAX_CAND];   // 48 KB
    int t = threadIdx.x;
    for (int k = t; k < MAX_CAND; k += 1024) bx[k] = cboxes[k];
    __syncthreads();

    const int lane = t & 63;
    const int wave = t >> 6;
    const int r0 = blockIdx.x * 64 + wave * 4;

    float4 bi[4]; float ai[4];
    #pragma unroll
    for (int u = 0; u < 4; ++u) {
        int rc = min(r0 + u, MAX_CAND - 1);
        bi[u] = bx[rc];
        ai[u] = __fmul_rn(__fsub_rn(bi[u].z, bi[u].x), __fsub_rn(bi[u].w, bi[u].y));
    }

    for (int w = blockIdx.x; w < NWORDS; ++w) {
        int jc = w * 64 + lane;
        bool jv = (jc < MAX_CAND);
        float4 bj = bx[jv ? jc : (MAX_CAND - 1)];
        float  aj = __fmul_rn(__fsub_rn(bj.z, bj.x), __fsub_rn(bj.w, bj.y));
        #pragma unroll
        for (int u = 0; u < 4; ++u) {
            int r = r0 + u;
            bool p = jv && (r < MAX_CAND) && (jc > r) && iou_gt(bi[u], ai[u], bj, aj);
            unsigned long long msk = __ballot(p);
            if (lane == 0 && r < MAX_CAND) sup[(size_t)r * NWORDS + w] = msk;
        }
    }
}

// ---------------------------------------------------------------------------
// K4: chunked greedy NMS over precomputed sup bits; early exit once kept>=300;
// nonzero-row skip; fixed-trip predicated fold; parallel output. (verified R3)
// ---------------------------------------------------------------------------
__global__ __launch_bounds__(1024) void k_nms_out(
    const unsigned long long* __restrict__ sup,
    const unsigned long long* __restrict__ kpm,
    const float4* __restrict__ cboxes, const float2* __restrict__ cscores,
    float* __restrict__ out)
{
    __shared__ unsigned long long buf[2][CHUNK_W];
    __shared__ unsigned long long kp[NWORDS + 1];
    __shared__ int sel[TOP_N];
    __shared__ int s_stop;

    int tid  = threadIdx.x;
    int lane = tid & 63;
    int wave = tid >> 6;

    for (int t = tid; t < TOP_N * 7; t += 1024) out[t] = 0.0f;
    for (int t = tid; t < TOP_N; t += 1024) sel[t] = -1;

    if (tid < NWORDS) kp[tid] = kpm[tid];

    {
        unsigned long long v0 = sup[tid];
        unsigned long long v1 = sup[tid + 1024];
        unsigned long long v2 = (tid + 2048 < CHUNK_W) ? sup[tid + 2048] : 0ull;
        buf[0][tid] = v0;
        buf[0][tid + 1024] = v1;
        if (tid + 2048 < CHUNK_W) buf[0][tid + 2048] = v2;
    }
    __syncthreads();

    int kept_total = 0;
    for (int w = 0; w < NWORDS; ++w) {
        int cur = w & 1;
        bool havnext = (w + 1 < NWORDS);

        unsigned long long v0 = 0, v1 = 0, v2 = 0;
        if (havnext) {
            const unsigned long long* src = sup + (size_t)(w + 1) * CHUNK_W;
            v0 = src[tid];
            v1 = src[tid + 1024];
            v2 = (tid + 2048 < CHUNK_W) ? src[tid + 2048] : 0ull;
        }

        if (wave == 0) {
            unsigned long long intra = buf[cur][lane * NWORDS + w];
            unsigned long long nz = __ballot(intra != 0ull);
            unsigned long long kw = kp[w];
            unsigned long long rem = kw & nz;
            while (rem) {
                int b = __ffsll((long long)rem) - 1;
                rem &= rem - 1;
                if ((kw >> b) & 1ull) {
                    unsigned long long row = __shfl(intra, b, 64);
                    kw  &= ~row;
                    rem &= ~row;
                }
            }
            if (lane == 0) kp[w] = kw;
            kept_total += __popcll(kw);
            bool stop = (kept_total >= TOP_N) || !havnext;
            if (lane == 0) s_stop = stop ? 1 : 0;

            if (!stop && lane < NWORDS && lane > w) {
                unsigned long long comb = 0;
                #pragma unroll 8
                for (int b = 0; b < 64; ++b) {
                    unsigned long long r = buf[cur][b * NWORDS + lane];
                    if ((kw >> b) & 1ull) comb |= r;
                }
                kp[lane] &= ~comb;
            }
        }

        if (havnext) {
            int nxt = cur ^ 1;
            buf[nxt][tid] = v0;
            buf[nxt][tid + 1024] = v1;
            if (tid + 2048 < CHUNK_W) buf[nxt][tid + 2048] = v2;
        }
        __syncthreads();
        if (s_stop) break;
    }

    if (wave == 0) {
        unsigned long long kw = (lane < NWORDS) ? kp[lane] : 0ull;
        int cnt = __popcll(kw);
        int pre = cnt;
        for (int d = 1; d < 64; d <<= 1) {
            int o = __shfl_up(pre, d, 64);
            if (lane >= d) pre += o;
        }
        int prefix = pre - cnt;
        while (kw && prefix < TOP_N) {
            int b = __ffsll((long long)kw) - 1;
            kw &= kw - 1;
            sel[prefix] = lane * 64 + b;
            prefix++;
        }
    }
    __syncthreads();

    if (tid < TOP_N) {
        int j = sel[tid];
        if (j >= 0) {
            float4 bx = cboxes[j];
            float2 sc = cscores[j];
            out[tid * 5 + 0] = 0.0f;
            out[tid * 5 + 1] = bx.x;
            out[tid * 5 + 2] = bx.y;
            out[tid * 5 + 3] = bx.z;
            out[tid * 5 + 4] = bx.w;
            out[TOP_N * 5 + tid * 2 + 0] = sc.x;
            out[TOP_N * 5 + tid * 2 + 1] = sc.y;
        }
    }
}

// ---------------------------------------------------------------------------
extern "C" void kernel_launch(void* const* d_in, const int* in_sizes, int n_in,
                              void* d_out, int out_size, void* d_ws, size_t ws_size,
                              hipStream_t stream) {
    const float* cls    = (const float*)d_in[0];
    const float* pred   = (const float*)d_in[1];
    const int*   iminfo = (const int*)d_in[2];
    float* out = (float*)d_out;

    char* p = (char*)d_ws;
    auto alloc = [&](size_t bytes) -> char* {
        char* q = p;
        p += (bytes + 255) & ~(size_t)255;
        return q;
    };
    float4* boxes  = (float4*)alloc((size_t)N * sizeof(float4));
    float2* scores = (float2*)alloc((size_t)N * sizeof(float2));
    unsigned long long* keys  = (unsigned long long*)alloc((size_t)N * 8);
    unsigned long long* skeys = (unsigned long long*)alloc((size_t)N * 8);
    float4* cboxes  = (float4*)alloc((size_t)MAX_CAND * sizeof(float4));
    float2* cscores = (float2*)alloc((size_t)MAX_CAND * sizeof(float2));
    unsigned long long* kpm = (unsigned long long*)alloc((size_t)NWORDS * 8);
    unsigned long long* sup = (unsigned long long*)alloc((size_t)MAX_CAND * NWORDS * 8);

    int nb = (N + 255) / 256;  // 68
    k_boxes <<<nb, 256, 0, stream>>>(cls, pred, iminfo, boxes, scores, keys);
    k_mid   <<<1, 1024, 0, stream>>>(keys, boxes, scores, skeys, cboxes, cscores, kpm);
    k_iou   <<<NWORDS, 1024, 0, stream>>>(cboxes, sup);
    k_nms_out<<<1, 1024, 0, stream>>>(sup, kpm, cboxes, cscores, out);
}

// Round 10
// 117.385 us; speedup vs baseline: 1.2260x; 1.2260x over previous
//
#include <hip/hip_runtime.h>
#include <stdint.h>

#define A 15
#define H_ 34
#define W_ 34
#define HW (H_*W_)
#define N (A*HW)            // 17340
#define MAX_CAND 3000
#define TOP_N 300
#define NWORDS 47           // ceil(3000/64)
#define CHUNK_W 3008        // 64 rows * 47 words per chunk
#define NBUCK 8000          // linear score buckets (monotone quantization)
#define JSLICE 4            // k_iou word-slices per chunk

__constant__ float c_aw[A] = {9.232984f, 16.0f, 27.712813f, 18.465969f, 32.0f, 55.425626f,
                              36.931937f, 64.0f, 110.851252f, 73.863875f, 128.0f, 221.702503f,
                              147.72775f, 256.0f, 443.405007f};
__constant__ float c_ah[A] = {27.72668f, 16.0f, 9.237604f, 55.453359f, 32.0f, 18.475209f,
                              110.906719f, 64.0f, 36.950417f, 221.813438f, 128.0f, 73.900834f,
                              443.626876f, 256.0f, 147.801669f};

// ---------------------------------------------------------------------------
// K1: decode boxes/scores; key = bucket(13) | score-bits(32) | ~idx(15).
// Exact reference op order; __f*_rn blocks FMA contraction. (verified R8)
// ---------------------------------------------------------------------------
__global__ __launch_bounds__(256) void k_boxes(
    const float* __restrict__ cls, const float* __restrict__ pred,
    const int* __restrict__ iminfo,
    float4* __restrict__ boxes, float2* __restrict__ scores,
    unsigned long long* __restrict__ keys)
{
    int m = blockIdx.x * 256 + threadIdx.x;
    if (m >= N) return;

    int a  = m % A;
    int hw = m / A;
    int w  = hw % W_;
    int h  = hw / W_;

    float ow = (float)iminfo[1];
    float oh = (float)iminfo[0];

    float aw = c_aw[a], ah = c_ah[a];
    float xm = __fmul_rn(-0.5f, __fsub_rn(aw, 1.0f));
    float ym = __fmul_rn(-0.5f, __fsub_rn(ah, 1.0f));
    float sxw = (float)(w * 8);
    float syh = (float)(h * 8);
    float x1 = __fadd_rn(sxw, xm);
    float y1 = __fadd_rn(syh, ym);
    float x2 = __fadd_rn(sxw, -xm);
    float y2 = __fadd_rn(syh, -ym);

    float widths  = __fadd_rn(__fsub_rn(x2, x1), 1.0f);
    float heights = __fadd_rn(__fsub_rn(y2, y1), 1.0f);
    float ctr_x = __fadd_rn(x1, __fmul_rn(0.5f, __fsub_rn(widths, 1.0f)));
    float ctr_y = __fadd_rn(y1, __fmul_rn(0.5f, __fsub_rn(heights, 1.0f)));

    const float std0 = 0.12677f,   std1 = 0.095741f, std2 = 0.3173f,    std3 = 0.281042f;
    const float mu0  = 0.000437f,  mu1  = 0.002586f, mu2  = -0.123953f, mu3  = -0.081469f;
    int pb = a * 4 * HW + hw;
    float d0 = __fadd_rn(__fmul_rn(pred[pb + 0 * HW], std0), mu0);
    float d1 = __fadd_rn(__fmul_rn(pred[pb + 1 * HW], std1), mu1);
    float d2 = __fadd_rn(__fmul_rn(pred[pb + 2 * HW], std2), mu2);
    float d3 = __fadd_rn(__fmul_rn(pred[pb + 3 * HW], std3), mu3);

    float pcx = __fadd_rn(__fmul_rn(d0, widths),  ctr_x);
    float pcy = __fadd_rn(__fmul_rn(d1, heights), ctr_y);
    float pw  = __fmul_rn(expf(d2), widths);
    float ph  = __fmul_rn(expf(d3), heights);

    float hpw = __fmul_rn(0.5f, __fsub_rn(pw, 1.0f));
    float hph = __fmul_rn(0.5f, __fsub_rn(ph, 1.0f));
    float bx1 = __fsub_rn(pcx, hpw);
    float by1 = __fsub_rn(pcy, hph);
    float bx2 = __fadd_rn(pcx, hpw);
    float by2 = __fadd_rn(pcy, hph);

    float ow1 = __fsub_rn(ow, 1.0f), oh1 = __fsub_rn(oh, 1.0f);
    bx1 = fminf(fmaxf(bx1, 0.0f), ow1);
    by1 = fminf(fmaxf(by1, 0.0f), oh1);
    bx2 = fminf(fmaxf(bx2, 0.0f), ow1);
    by2 = fminf(fmaxf(by2, 0.0f), oh1);

    float s0 = cls[a * HW + hw];
    float s1 = cls[(A + a) * HW + hw];

    float wsv = __fadd_rn(__fsub_rn(bx2, bx1), 1.0f);
    float hsv = __fadd_rn(__fsub_rn(by2, by1), 1.0f);
    bool keep = (s1 > 0.2f) && ((wsv >= 6.16056f) || (hsv >= 6.16056f));
    float masked = keep ? s1 : -1e30f;

    boxes[m]  = make_float4(bx1, by1, bx2, by2);
    scores[m] = make_float2(s0, s1);

    int bucket = keep ? (1 + min(NBUCK - 2, max(0, (int)(s1 * (float)(NBUCK - 2))))) : 0;
    unsigned int fb = __float_as_uint(masked);
    fb = (fb & 0x80000000u) ? ~fb : (fb | 0x80000000u);
    keys[m] = ((unsigned long long)bucket << 51)
            | ((unsigned long long)fb << 15)
            | (unsigned long long)((~m) & 0x7fff);
}

// ---------------------------------------------------------------------------
// K2: single block, 1024 threads. LDS histogram over 8000 buckets ->
// suffix scan -> threshold bucket B -> bucket-grouped compact -> rank =
// base[b] + tiny within-bucket compare -> scatter. (verified R8)
// ---------------------------------------------------------------------------
__global__ __launch_bounds__(1024) void k_mid(
    const unsigned long long* __restrict__ keys,
    const float4* __restrict__ boxes, const float2* __restrict__ scores,
    unsigned long long* __restrict__ skeys,
    float4* __restrict__ cboxes, float2* __restrict__ cscores,
    unsigned long long* __restrict__ kpm)
{
    __shared__ int s_base[NBUCK];               // counts -> suffix bases
    __shared__ int s_off[NBUCK];                // tsum alias, then bucket offsets
    __shared__ unsigned long long s_kpm[NWORDS];
    __shared__ int s_B[1];

    const int t = threadIdx.x;

    for (int k = t; k < NBUCK; k += 1024) s_base[k] = 0;
    if (t < NWORDS) s_kpm[t] = 0ull;
    __syncthreads();

    unsigned long long myk[17];
    #pragma unroll
    for (int q = 0; q < 17; ++q) {
        int i = q * 1024 + t;
        myk[q] = (i < N) ? keys[i] : 0ull;
        if (i < N) atomicAdd(&s_base[(int)(myk[q] >> 51)], 1);
    }
    __syncthreads();

    int c0=0,c1=0,c2=0,c3=0,c4=0,c5=0,c6=0,c7=0;
    int gsum = 0;
    const int g0 = t * 8;
    if (t < NBUCK / 8) {
        c0 = s_base[g0+0]; c1 = s_base[g0+1]; c2 = s_base[g0+2]; c3 = s_base[g0+3];
        c4 = s_base[g0+4]; c5 = s_base[g0+5]; c6 = s_base[g0+6]; c7 = s_base[g0+7];
        gsum = c0+c1+c2+c3+c4+c5+c6+c7;
    }
    int* tsum = s_off;
    tsum[t] = gsum;
    __syncthreads();
    for (int d = 1; d < 1024; d <<= 1) {
        int v = (t + d < 1024) ? tsum[t + d] : 0;
        __syncthreads();
        tsum[t] += v;
        __syncthreads();
    }
    int above = (t < 1023) ? tsum[t + 1] : 0;

    if (t < NBUCK / 8) {
        int run = above;
        #define STEP(q, cq) { s_base[g0+q] = run; \
            if (run < MAX_CAND && run + cq >= MAX_CAND) s_B[0] = g0 + q; \
            run += cq; }
        STEP(7, c7) STEP(6, c6) STEP(5, c5) STEP(4, c4)
        STEP(3, c3) STEP(2, c2) STEP(1, c1) STEP(0, c0)
        #undef STEP
    }
    __syncthreads();
    const int B = s_B[0];
    for (int k = t; k < NBUCK; k += 1024) s_off[k] = 0;
    __syncthreads();

    #pragma unroll
    for (int q = 0; q < 17; ++q) {
        int i = q * 1024 + t;
        if (i < N) {
            int b = (int)(myk[q] >> 51);
            if (b >= B) {
                int slot = s_base[b] + atomicAdd(&s_off[b], 1);
                skeys[slot] = myk[q];
            }
        }
    }
    __syncthreads();
    const int S = s_base[B] + s_off[B];

    for (int p = t; p < S; p += 1024) {
        unsigned long long k = skeys[p];
        int b  = (int)(k >> 51);
        int lo = s_base[b];
        int hi = lo + s_off[b];
        int cg = 0;
        for (int j = lo; j < hi; ++j) cg += (skeys[j] > k) ? 1 : 0;
        int rank = lo + cg;
        if (rank < MAX_CAND) {
            int orig = ((int)k & 0x7fff) ^ 0x7fff;
            cboxes[rank]  = boxes[orig];
            cscores[rank] = scores[orig];
            if (b >= 1) atomicOr(&s_kpm[rank >> 6], 1ull << (rank & 63));
        }
    }
    __syncthreads();
    if (t < NWORDS) kpm[t] = s_kpm[t];
}

// ---------------------------------------------------------------------------
// K3: suppression bitmask, register-blocked + triangular + j-sliced.
// grid (c, s) = (chunk, word-slice): rows 64c..64c+63, words w = c+s, c+s+4,...
// (words < c are never read downstream). 16 waves x 4 rows/wave; one LDS read
// of bj per lane serves 4 register-resident rows. 188 blocks -> 4x the CUs
// of R9 (k_iou was VALU-issue-bound on 47 CUs).
// ---------------------------------------------------------------------------
__device__ __forceinline__ bool iou_gt(
    float4 bi, float ai, float4 bj, float aj)
{
    float iw = fmaxf(__fsub_rn(fminf(bi.z, bj.z), fmaxf(bi.x, bj.x)), 0.0f);
    float ih = fmaxf(__fsub_rn(fminf(bi.w, bj.w), fmaxf(bi.y, bj.y)), 0.0f);
    float inter = __fmul_rn(iw, ih);
    float denom = fmaxf(__fsub_rn(__fadd_rn(ai, aj), inter), 1e-12f);
    return (inter / denom) > 0.7f;
}

__global__ __launch_bounds__(1024) void k_iou(
    const float4* __restrict__ cboxes, unsigned long long* __restrict__ sup)
{
    __shared__ float4 bx[MAX_CAND];   // 48 KB
    int t = threadIdx.x;
    for (int k = t; k < MAX_CAND; k += 1024) bx[k] = cboxes[k];
    __syncthreads();

    const int lane = t & 63;
    const int wave = t >> 6;
    const int c = blockIdx.x;          // row chunk
    const int s = blockIdx.y;          // word slice
    const int r0 = c * 64 + wave * 4;

    float4 bi[4]; float ai[4];
    #pragma unroll
    for (int u = 0; u < 4; ++u) {
        int rc = min(r0 + u, MAX_CAND - 1);
        bi[u] = bx[rc];
        ai[u] = __fmul_rn(__fsub_rn(bi[u].z, bi[u].x), __fsub_rn(bi[u].w, bi[u].y));
    }

    for (int w = c + s; w < NWORDS; w += JSLICE) {
        int jc = w * 64 + lane;
        bool jv = (jc < MAX_CAND);
        float4 bj = bx[jv ? jc : (MAX_CAND - 1)];
        float  aj = __fmul_rn(__fsub_rn(bj.z, bj.x), __fsub_rn(bj.w, bj.y));
        #pragma unroll
        for (int u = 0; u < 4; ++u) {
            int r = r0 + u;
            bool p = jv && (r < MAX_CAND) && (jc > r) && iou_gt(bi[u], ai[u], bj, aj);
            unsigned long long msk = __ballot(p);
            if (lane == 0 && r < MAX_CAND) sup[(size_t)r * NWORDS + w] = msk;
        }
    }
}

// ---------------------------------------------------------------------------
// K4: chunked greedy NMS over precomputed sup bits; early exit once kept>=300;
// nonzero-row skip; fixed-trip predicated fold; parallel output. (verified R3)
// ---------------------------------------------------------------------------
__global__ __launch_bounds__(1024) void k_nms_out(
    const unsigned long long* __restrict__ sup,
    const unsigned long long* __restrict__ kpm,
    const float4* __restrict__ cboxes, const float2* __restrict__ cscores,
    float* __restrict__ out)
{
    __shared__ unsigned long long buf[2][CHUNK_W];
    __shared__ unsigned long long kp[NWORDS + 1];
    __shared__ int sel[TOP_N];
    __shared__ int s_stop;

    int tid  = threadIdx.x;
    int lane = tid & 63;
    int wave = tid >> 6;

    for (int t = tid; t < TOP_N * 7; t += 1024) out[t] = 0.0f;
    for (int t = tid; t < TOP_N; t += 1024) sel[t] = -1;

    if (tid < NWORDS) kp[tid] = kpm[tid];

    {
        unsigned long long v0 = sup[tid];
        unsigned long long v1 = sup[tid + 1024];
        unsigned long long v2 = (tid + 2048 < CHUNK_W) ? sup[tid + 2048] : 0ull;
        buf[0][tid] = v0;
        buf[0][tid + 1024] = v1;
        if (tid + 2048 < CHUNK_W) buf[0][tid + 2048] = v2;
    }
    __syncthreads();

    int kept_total = 0;
    for (int w = 0; w < NWORDS; ++w) {
        int cur = w & 1;
        bool havnext = (w + 1 < NWORDS);

        unsigned long long v0 = 0, v1 = 0, v2 = 0;
        if (havnext) {
            const unsigned long long* src = sup + (size_t)(w + 1) * CHUNK_W;
            v0 = src[tid];
            v1 = src[tid + 1024];
            v2 = (tid + 2048 < CHUNK_W) ? src[tid + 2048] : 0ull;
        }

        if (wave == 0) {
            unsigned long long intra = buf[cur][lane * NWORDS + w];
            unsigned long long nz = __ballot(intra != 0ull);
            unsigned long long kw = kp[w];
            unsigned long long rem = kw & nz;
            while (rem) {
                int b = __ffsll((long long)rem) - 1;
                rem &= rem - 1;
                if ((kw >> b) & 1ull) {
                    unsigned long long row = __shfl(intra, b, 64);
                    kw  &= ~row;
                    rem &= ~row;
                }
            }
            if (lane == 0) kp[w] = kw;
            kept_total += __popcll(kw);
            bool stop = (kept_total >= TOP_N) || !havnext;
            if (lane == 0) s_stop = stop ? 1 : 0;

            if (!stop && lane < NWORDS && lane > w) {
                unsigned long long comb = 0;
                #pragma unroll 8
                for (int b = 0; b < 64; ++b) {
                    unsigned long long r = buf[cur][b * NWORDS + lane];
                    if ((kw >> b) & 1ull) comb |= r;
                }
                kp[lane] &= ~comb;
            }
        }

        if (havnext) {
            int nxt = cur ^ 1;
            buf[nxt][tid] = v0;
            buf[nxt][tid + 1024] = v1;
            if (tid + 2048 < CHUNK_W) buf[nxt][tid + 2048] = v2;
        }
        __syncthreads();
        if (s_stop) break;
    }

    if (wave == 0) {
        unsigned long long kw = (lane < NWORDS) ? kp[lane] : 0ull;
        int cnt = __popcll(kw);
        int pre = cnt;
        for (int d = 1; d < 64; d <<= 1) {
            int o = __shfl_up(pre, d, 64);
            if (lane >= d) pre += o;
        }
        int prefix = pre - cnt;
        while (kw && prefix < TOP_N) {
            int b = __ffsll((long long)kw) - 1;
            kw &= kw - 1;
            sel[prefix] = lane * 64 + b;
            prefix++;
        }
    }
    __syncthreads();

    if (tid < TOP_N) {
        int j = sel[tid];
        if (j >= 0) {
            float4 bx = cboxes[j];
            float2 sc = cscores[j];
            out[tid * 5 + 0] = 0.0f;
            out[tid * 5 + 1] = bx.x;
            out[tid * 5 + 2] = bx.y;
            out[tid * 5 + 3] = bx.z;
            out[tid * 5 + 4] = bx.w;
            out[TOP_N * 5 + tid * 2 + 0] = sc.x;
            out[TOP_N * 5 + tid * 2 + 1] = sc.y;
        }
    }
}

// ---------------------------------------------------------------------------
extern "C" void kernel_launch(void* const* d_in, const int* in_sizes, int n_in,
                              void* d_out, int out_size, void* d_ws, size_t ws_size,
                              hipStream_t stream) {
    const float* cls    = (const float*)d_in[0];
    const float* pred   = (const float*)d_in[1];
    const int*   iminfo = (const int*)d_in[2];
    float* out = (float*)d_out;

    char* p = (char*)d_ws;
    auto alloc = [&](size_t bytes) -> char* {
        char* q = p;
        p += (bytes + 255) & ~(size_t)255;
        return q;
    };
    float4* boxes  = (float4*)alloc((size_t)N * sizeof(float4));
    float2* scores = (float2*)alloc((size_t)N * sizeof(float2));
    unsigned long long* keys  = (unsigned long long*)alloc((size_t)N * 8);
    unsigned long long* skeys = (unsigned long long*)alloc((size_t)N * 8);
    float4* cboxes  = (float4*)alloc((size_t)MAX_CAND * sizeof(float4));
    float2* cscores = (float2*)alloc((size_t)MAX_CAND * sizeof(float2));
    unsigned long long* kpm = (unsigned long long*)alloc((size_t)NWORDS * 8);
    unsigned long long* sup = (unsigned long long*)alloc((size_t)MAX_CAND * NWORDS * 8);

    int nb = (N + 255) / 256;  // 68
    k_boxes <<<nb, 256, 0, stream>>>(cls, pred, iminfo, boxes, scores, keys);
    k_mid   <<<1, 1024, 0, stream>>>(keys, boxes, scores, skeys, cboxes, cscores, kpm);
    k_iou   <<<dim3(NWORDS, JSLICE), 1024, 0, stream>>>(cboxes, sup);
    k_nms_out<<<1, 1024, 0, stream>>>(sup, kpm, cboxes, cscores, out);
}

// Round 11
// 114.938 us; speedup vs baseline: 1.2521x; 1.0213x over previous
//
#include <hip/hip_runtime.h>
#include <stdint.h>

#define A 15
#define H_ 34
#define W_ 34
#define HW (H_*W_)
#define N (A*HW)            // 17340
#define MAX_CAND 3000
#define TOP_N 300
#define NWORDS 47           // ceil(3000/64)
#define CHUNK_W 3008        // 64 rows * 47 words per chunk
#define NBUCK 8000          // linear score buckets (monotone quantization)
#define JSLICE 8            // k_iou word-slices per chunk (R10: 4 -> 8, issue-bound)

__constant__ float c_aw[A] = {9.232984f, 16.0f, 27.712813f, 18.465969f, 32.0f, 55.425626f,
                              36.931937f, 64.0f, 110.851252f, 73.863875f, 128.0f, 221.702503f,
                              147.72775f, 256.0f, 443.405007f};
__constant__ float c_ah[A] = {27.72668f, 16.0f, 9.237604f, 55.453359f, 32.0f, 18.475209f,
                              110.906719f, 64.0f, 36.950417f, 221.813438f, 128.0f, 73.900834f,
                              443.626876f, 256.0f, 147.801669f};

// ---------------------------------------------------------------------------
// K1: decode boxes/scores; key = bucket(13) | score-bits(32) | ~idx(15).
// Exact reference op order; __f*_rn blocks FMA contraction. (verified R8)
// ---------------------------------------------------------------------------
__global__ __launch_bounds__(256) void k_boxes(
    const float* __restrict__ cls, const float* __restrict__ pred,
    const int* __restrict__ iminfo,
    float4* __restrict__ boxes, float2* __restrict__ scores,
    unsigned long long* __restrict__ keys)
{
    int m = blockIdx.x * 256 + threadIdx.x;
    if (m >= N) return;

    int a  = m % A;
    int hw = m / A;
    int w  = hw % W_;
    int h  = hw / W_;

    float ow = (float)iminfo[1];
    float oh = (float)iminfo[0];

    float aw = c_aw[a], ah = c_ah[a];
    float xm = __fmul_rn(-0.5f, __fsub_rn(aw, 1.0f));
    float ym = __fmul_rn(-0.5f, __fsub_rn(ah, 1.0f));
    float sxw = (float)(w * 8);
    float syh = (float)(h * 8);
    float x1 = __fadd_rn(sxw, xm);
    float y1 = __fadd_rn(syh, ym);
    float x2 = __fadd_rn(sxw, -xm);
    float y2 = __fadd_rn(syh, -ym);

    float widths  = __fadd_rn(__fsub_rn(x2, x1), 1.0f);
    float heights = __fadd_rn(__fsub_rn(y2, y1), 1.0f);
    float ctr_x = __fadd_rn(x1, __fmul_rn(0.5f, __fsub_rn(widths, 1.0f)));
    float ctr_y = __fadd_rn(y1, __fmul_rn(0.5f, __fsub_rn(heights, 1.0f)));

    const float std0 = 0.12677f,   std1 = 0.095741f, std2 = 0.3173f,    std3 = 0.281042f;
    const float mu0  = 0.000437f,  mu1  = 0.002586f, mu2  = -0.123953f, mu3  = -0.081469f;
    int pb = a * 4 * HW + hw;
    float d0 = __fadd_rn(__fmul_rn(pred[pb + 0 * HW], std0), mu0);
    float d1 = __fadd_rn(__fmul_rn(pred[pb + 1 * HW], std1), mu1);
    float d2 = __fadd_rn(__fmul_rn(pred[pb + 2 * HW], std2), mu2);
    float d3 = __fadd_rn(__fmul_rn(pred[pb + 3 * HW], std3), mu3);

    float pcx = __fadd_rn(__fmul_rn(d0, widths),  ctr_x);
    float pcy = __fadd_rn(__fmul_rn(d1, heights), ctr_y);
    float pw  = __fmul_rn(expf(d2), widths);
    float ph  = __fmul_rn(expf(d3), heights);

    float hpw = __fmul_rn(0.5f, __fsub_rn(pw, 1.0f));
    float hph = __fmul_rn(0.5f, __fsub_rn(ph, 1.0f));
    float bx1 = __fsub_rn(pcx, hpw);
    float by1 = __fsub_rn(pcy, hph);
    float bx2 = __fadd_rn(pcx, hpw);
    float by2 = __fadd_rn(pcy, hph);

    float ow1 = __fsub_rn(ow, 1.0f), oh1 = __fsub_rn(oh, 1.0f);
    bx1 = fminf(fmaxf(bx1, 0.0f), ow1);
    by1 = fminf(fmaxf(by1, 0.0f), oh1);
    bx2 = fminf(fmaxf(bx2, 0.0f), ow1);
    by2 = fminf(fmaxf(by2, 0.0f), oh1);

    float s0 = cls[a * HW + hw];
    float s1 = cls[(A + a) * HW + hw];

    float wsv = __fadd_rn(__fsub_rn(bx2, bx1), 1.0f);
    float hsv = __fadd_rn(__fsub_rn(by2, by1), 1.0f);
    bool keep = (s1 > 0.2f) && ((wsv >= 6.16056f) || (hsv >= 6.16056f));
    float masked = keep ? s1 : -1e30f;

    boxes[m]  = make_float4(bx1, by1, bx2, by2);
    scores[m] = make_float2(s0, s1);

    int bucket = keep ? (1 + min(NBUCK - 2, max(0, (int)(s1 * (float)(NBUCK - 2))))) : 0;
    unsigned int fb = __float_as_uint(masked);
    fb = (fb & 0x80000000u) ? ~fb : (fb | 0x80000000u);
    keys[m] = ((unsigned long long)bucket << 51)
            | ((unsigned long long)fb << 15)
            | (unsigned long long)((~m) & 0x7fff);
}

// ---------------------------------------------------------------------------
// K2: single block, 1024 threads. LDS histogram over 8000 buckets ->
// suffix scan -> threshold bucket B -> bucket-grouped compact -> rank =
// base[b] + tiny within-bucket compare -> scatter. (verified R8)
// ---------------------------------------------------------------------------
__global__ __launch_bounds__(1024) void k_mid(
    const unsigned long long* __restrict__ keys,
    const float4* __restrict__ boxes, const float2* __restrict__ scores,
    unsigned long long* __restrict__ skeys,
    float4* __restrict__ cboxes, float2* __restrict__ cscores,
    unsigned long long* __restrict__ kpm)
{
    __shared__ int s_base[NBUCK];               // counts -> suffix bases
    __shared__ int s_off[NBUCK];                // tsum alias, then bucket offsets
    __shared__ unsigned long long s_kpm[NWORDS];
    __shared__ int s_B[1];

    const int t = threadIdx.x;

    for (int k = t; k < NBUCK; k += 1024) s_base[k] = 0;
    if (t < NWORDS) s_kpm[t] = 0ull;
    __syncthreads();

    unsigned long long myk[17];
    #pragma unroll
    for (int q = 0; q < 17; ++q) {
        int i = q * 1024 + t;
        myk[q] = (i < N) ? keys[i] : 0ull;
        if (i < N) atomicAdd(&s_base[(int)(myk[q] >> 51)], 1);
    }
    __syncthreads();

    int c0=0,c1=0,c2=0,c3=0,c4=0,c5=0,c6=0,c7=0;
    int gsum = 0;
    const int g0 = t * 8;
    if (t < NBUCK / 8) {
        c0 = s_base[g0+0]; c1 = s_base[g0+1]; c2 = s_base[g0+2]; c3 = s_base[g0+3];
        c4 = s_base[g0+4]; c5 = s_base[g0+5]; c6 = s_base[g0+6]; c7 = s_base[g0+7];
        gsum = c0+c1+c2+c3+c4+c5+c6+c7;
    }
    int* tsum = s_off;
    tsum[t] = gsum;
    __syncthreads();
    for (int d = 1; d < 1024; d <<= 1) {
        int v = (t + d < 1024) ? tsum[t + d] : 0;
        __syncthreads();
        tsum[t] += v;
        __syncthreads();
    }
    int above = (t < 1023) ? tsum[t + 1] : 0;

    if (t < NBUCK / 8) {
        int run = above;
        #define STEP(q, cq) { s_base[g0+q] = run; \
            if (run < MAX_CAND && run + cq >= MAX_CAND) s_B[0] = g0 + q; \
            run += cq; }
        STEP(7, c7) STEP(6, c6) STEP(5, c5) STEP(4, c4)
        STEP(3, c3) STEP(2, c2) STEP(1, c1) STEP(0, c0)
        #undef STEP
    }
    __syncthreads();
    const int B = s_B[0];
    for (int k = t; k < NBUCK; k += 1024) s_off[k] = 0;
    __syncthreads();

    #pragma unroll
    for (int q = 0; q < 17; ++q) {
        int i = q * 1024 + t;
        if (i < N) {
            int b = (int)(myk[q] >> 51);
            if (b >= B) {
                int slot = s_base[b] + atomicAdd(&s_off[b], 1);
                skeys[slot] = myk[q];
            }
        }
    }
    __syncthreads();
    const int S = s_base[B] + s_off[B];

    for (int p = t; p < S; p += 1024) {
        unsigned long long k = skeys[p];
        int b  = (int)(k >> 51);
        int lo = s_base[b];
        int hi = lo + s_off[b];
        int cg = 0;
        for (int j = lo; j < hi; ++j) cg += (skeys[j] > k) ? 1 : 0;
        int rank = lo + cg;
        if (rank < MAX_CAND) {
            int orig = ((int)k & 0x7fff) ^ 0x7fff;
            cboxes[rank]  = boxes[orig];
            cscores[rank] = scores[orig];
            if (b >= 1) atomicOr(&s_kpm[rank >> 6], 1ull << (rank & 63));
        }
    }
    __syncthreads();
    if (t < NWORDS) kpm[t] = s_kpm[t];
}

// ---------------------------------------------------------------------------
// K3: suppression bitmask, register-blocked + triangular + j-sliced.
// grid (c, s) = (chunk, word-slice): rows 64c..64c+63, words w = c+s, step 8.
// (words < c are never read downstream). 16 waves x 4 rows/wave; one LDS read
// of bj per lane serves 4 register-resident rows. 376 blocks (VALU-issue-
// bound kernel: issue slots scale with active CUs -- R10 A/B: 47->188 blocks
// gave 42->12 us at constant total work).
// ---------------------------------------------------------------------------
__device__ __forceinline__ bool iou_gt(
    float4 bi, float ai, float4 bj, float aj)
{
    float iw = fmaxf(__fsub_rn(fminf(bi.z, bj.z), fmaxf(bi.x, bj.x)), 0.0f);
    float ih = fmaxf(__fsub_rn(fminf(bi.w, bj.w), fmaxf(bi.y, bj.y)), 0.0f);
    float inter = __fmul_rn(iw, ih);
    float denom = fmaxf(__fsub_rn(__fadd_rn(ai, aj), inter), 1e-12f);
    return (inter / denom) > 0.7f;
}

__global__ __launch_bounds__(1024) void k_iou(
    const float4* __restrict__ cboxes, unsigned long long* __restrict__ sup)
{
    __shared__ float4 bx[MAX_CAND];   // 48 KB
    int t = threadIdx.x;
    for (int k = t; k < MAX_CAND; k += 1024) bx[k] = cboxes[k];
    __syncthreads();

    const int lane = t & 63;
    const int wave = t >> 6;
    const int c = blockIdx.x;          // row chunk
    const int s = blockIdx.y;          // word slice
    const int r0 = c * 64 + wave * 4;

    float4 bi[4]; float ai[4];
    #pragma unroll
    for (int u = 0; u < 4; ++u) {
        int rc = min(r0 + u, MAX_CAND - 1);
        bi[u] = bx[rc];
        ai[u] = __fmul_rn(__fsub_rn(bi[u].z, bi[u].x), __fsub_rn(bi[u].w, bi[u].y));
    }

    for (int w = c + s; w < NWORDS; w += JSLICE) {
        int jc = w * 64 + lane;
        bool jv = (jc < MAX_CAND);
        float4 bj = bx[jv ? jc : (MAX_CAND - 1)];
        float  aj = __fmul_rn(__fsub_rn(bj.z, bj.x), __fsub_rn(bj.w, bj.y));
        #pragma unroll
        for (int u = 0; u < 4; ++u) {
            int r = r0 + u;
            bool p = jv && (r < MAX_CAND) && (jc > r) && iou_gt(bi[u], ai[u], bj, aj);
            unsigned long long msk = __ballot(p);
            if (lane == 0 && r < MAX_CAND) sup[(size_t)r * NWORDS + w] = msk;
        }
    }
}

// ---------------------------------------------------------------------------
// K4: chunked greedy NMS over precomputed sup bits; early exit once kept>=300;
// nonzero-row skip; fixed-trip predicated fold; parallel output. (verified R3)
// ---------------------------------------------------------------------------
__global__ __launch_bounds__(1024) void k_nms_out(
    const unsigned long long* __restrict__ sup,
    const unsigned long long* __restrict__ kpm,
    const float4* __restrict__ cboxes, const float2* __restrict__ cscores,
    float* __restrict__ out)
{
    __shared__ unsigned long long buf[2][CHUNK_W];
    __shared__ unsigned long long kp[NWORDS + 1];
    __shared__ int sel[TOP_N];
    __shared__ int s_stop;

    int tid  = threadIdx.x;
    int lane = tid & 63;
    int wave = tid >> 6;

    for (int t = tid; t < TOP_N * 7; t += 1024) out[t] = 0.0f;
    for (int t = tid; t < TOP_N; t += 1024) sel[t] = -1;

    if (tid < NWORDS) kp[tid] = kpm[tid];

    {
        unsigned long long v0 = sup[tid];
        unsigned long long v1 = sup[tid + 1024];
        unsigned long long v2 = (tid + 2048 < CHUNK_W) ? sup[tid + 2048] : 0ull;
        buf[0][tid] = v0;
        buf[0][tid + 1024] = v1;
        if (tid + 2048 < CHUNK_W) buf[0][tid + 2048] = v2;
    }
    __syncthreads();

    int kept_total = 0;
    for (int w = 0; w < NWORDS; ++w) {
        int cur = w & 1;
        bool havnext = (w + 1 < NWORDS);

        unsigned long long v0 = 0, v1 = 0, v2 = 0;
        if (havnext) {
            const unsigned long long* src = sup + (size_t)(w + 1) * CHUNK_W;
            v0 = src[tid];
            v1 = src[tid + 1024];
            v2 = (tid + 2048 < CHUNK_W) ? src[tid + 2048] : 0ull;
        }

        if (wave == 0) {
            unsigned long long intra = buf[cur][lane * NWORDS + w];
            unsigned long long nz = __ballot(intra != 0ull);
            unsigned long long kw = kp[w];
            unsigned long long rem = kw & nz;
            while (rem) {
                int b = __ffsll((long long)rem) - 1;
                rem &= rem - 1;
                if ((kw >> b) & 1ull) {
                    unsigned long long row = __shfl(intra, b, 64);
                    kw  &= ~row;
                    rem &= ~row;
                }
            }
            if (lane == 0) kp[w] = kw;
            kept_total += __popcll(kw);
            bool stop = (kept_total >= TOP_N) || !havnext;
            if (lane == 0) s_stop = stop ? 1 : 0;

            if (!stop && lane < NWORDS && lane > w) {
                unsigned long long comb = 0;
                #pragma unroll 8
                for (int b = 0; b < 64; ++b) {
                    unsigned long long r = buf[cur][b * NWORDS + lane];
                    if ((kw >> b) & 1ull) comb |= r;
                }
                kp[lane] &= ~comb;
            }
        }

        if (havnext) {
            int nxt = cur ^ 1;
            buf[nxt][tid] = v0;
            buf[nxt][tid + 1024] = v1;
            if (tid + 2048 < CHUNK_W) buf[nxt][tid + 2048] = v2;
        }
        __syncthreads();
        if (s_stop) break;
    }

    if (wave == 0) {
        unsigned long long kw = (lane < NWORDS) ? kp[lane] : 0ull;
        int cnt = __popcll(kw);
        int pre = cnt;
        for (int d = 1; d < 64; d <<= 1) {
            int o = __shfl_up(pre, d, 64);
            if (lane >= d) pre += o;
        }
        int prefix = pre - cnt;
        while (kw && prefix < TOP_N) {
            int b = __ffsll((long long)kw) - 1;
            kw &= kw - 1;
            sel[prefix] = lane * 64 + b;
            prefix++;
        }
    }
    __syncthreads();

    if (tid < TOP_N) {
        int j = sel[tid];
        if (j >= 0) {
            float4 bx = cboxes[j];
            float2 sc = cscores[j];
            out[tid * 5 + 0] = 0.0f;
            out[tid * 5 + 1] = bx.x;
            out[tid * 5 + 2] = bx.y;
            out[tid * 5 + 3] = bx.z;
            out[tid * 5 + 4] = bx.w;
            out[TOP_N * 5 + tid * 2 + 0] = sc.x;
            out[TOP_N * 5 + tid * 2 + 1] = sc.y;
        }
    }
}

// ---------------------------------------------------------------------------
extern "C" void kernel_launch(void* const* d_in, const int* in_sizes, int n_in,
                              void* d_out, int out_size, void* d_ws, size_t ws_size,
                              hipStream_t stream) {
    const float* cls    = (const float*)d_in[0];
    const float* pred   = (const float*)d_in[1];
    const int*   iminfo = (const int*)d_in[2];
    float* out = (float*)d_out;

    char* p = (char*)d_ws;
    auto alloc = [&](size_t bytes) -> char* {
        char* q = p;
        p += (bytes + 255) & ~(size_t)255;
        return q;
    };
    float4* boxes  = (float4*)alloc((size_t)N * sizeof(float4));
    float2* scores = (float2*)alloc((size_t)N * sizeof(float2));
    unsigned long long* keys  = (unsigned long long*)alloc((size_t)N * 8);
    unsigned long long* skeys = (unsigned long long*)alloc((size_t)N * 8);
    float4* cboxes  = (float4*)alloc((size_t)MAX_CAND * sizeof(float4));
    float2* cscores = (float2*)alloc((size_t)MAX_CAND * sizeof(float2));
    unsigned long long* kpm = (unsigned long long*)alloc((size_t)NWORDS * 8);
    unsigned long long* sup = (unsigned long long*)alloc((size_t)MAX_CAND * NWORDS * 8);

    int nb = (N + 255) / 256;  // 68
    k_boxes <<<nb, 256, 0, stream>>>(cls, pred, iminfo, boxes, scores, keys);
    k_mid   <<<1, 1024, 0, stream>>>(keys, boxes, scores, skeys, cboxes, cscores, kpm);
    k_iou   <<<dim3(NWORDS, JSLICE), 1024, 0, stream>>>(cboxes, sup);
    k_nms_out<<<1, 1024, 0, stream>>>(sup, kpm, cboxes, cscores, out);
}

// Round 12
// 111.561 us; speedup vs baseline: 1.2900x; 1.0303x over previous
//
#include <hip/hip_runtime.h>
#include <stdint.h>

#define A 15
#define H_ 34
#define W_ 34
#define HW (H_*W_)
#define N (A*HW)            // 17340
#define MAX_CAND 3000
#define TOP_N 300
#define NWORDS 47           // ceil(3000/64)
#define CHUNK_W 3008        // 64 rows * 47 words per chunk
#define NBUCK 8000          // linear score buckets (monotone quantization)
#define JSLICE 8            // k_iou word-slices per chunk
#define SCAP 4224           // LDS-resident compacted keys cap (S typical ~3030)

__constant__ float c_aw[A] = {9.232984f, 16.0f, 27.712813f, 18.465969f, 32.0f, 55.425626f,
                              36.931937f, 64.0f, 110.851252f, 73.863875f, 128.0f, 221.702503f,
                              147.72775f, 256.0f, 443.405007f};
__constant__ float c_ah[A] = {27.72668f, 16.0f, 9.237604f, 55.453359f, 32.0f, 18.475209f,
                              110.906719f, 64.0f, 36.950417f, 221.813438f, 128.0f, 73.900834f,
                              443.626876f, 256.0f, 147.801669f};

// ---------------------------------------------------------------------------
// K1: decode boxes/scores; key = bucket(13) | score-bits(32) | ~idx(15).
// Exact reference op order; __f*_rn blocks FMA contraction. (verified R8)
// ---------------------------------------------------------------------------
__global__ __launch_bounds__(256) void k_boxes(
    const float* __restrict__ cls, const float* __restrict__ pred,
    const int* __restrict__ iminfo,
    float4* __restrict__ boxes, float2* __restrict__ scores,
    unsigned long long* __restrict__ keys)
{
    int m = blockIdx.x * 256 + threadIdx.x;
    if (m >= N) return;

    int a  = m % A;
    int hw = m / A;
    int w  = hw % W_;
    int h  = hw / W_;

    float ow = (float)iminfo[1];
    float oh = (float)iminfo[0];

    float aw = c_aw[a], ah = c_ah[a];
    float xm = __fmul_rn(-0.5f, __fsub_rn(aw, 1.0f));
    float ym = __fmul_rn(-0.5f, __fsub_rn(ah, 1.0f));
    float sxw = (float)(w * 8);
    float syh = (float)(h * 8);
    float x1 = __fadd_rn(sxw, xm);
    float y1 = __fadd_rn(syh, ym);
    float x2 = __fadd_rn(sxw, -xm);
    float y2 = __fadd_rn(syh, -ym);

    float widths  = __fadd_rn(__fsub_rn(x2, x1), 1.0f);
    float heights = __fadd_rn(__fsub_rn(y2, y1), 1.0f);
    float ctr_x = __fadd_rn(x1, __fmul_rn(0.5f, __fsub_rn(widths, 1.0f)));
    float ctr_y = __fadd_rn(y1, __fmul_rn(0.5f, __fsub_rn(heights, 1.0f)));

    const float std0 = 0.12677f,   std1 = 0.095741f, std2 = 0.3173f,    std3 = 0.281042f;
    const float mu0  = 0.000437f,  mu1  = 0.002586f, mu2  = -0.123953f, mu3  = -0.081469f;
    int pb = a * 4 * HW + hw;
    float d0 = __fadd_rn(__fmul_rn(pred[pb + 0 * HW], std0), mu0);
    float d1 = __fadd_rn(__fmul_rn(pred[pb + 1 * HW], std1), mu1);
    float d2 = __fadd_rn(__fmul_rn(pred[pb + 2 * HW], std2), mu2);
    float d3 = __fadd_rn(__fmul_rn(pred[pb + 3 * HW], std3), mu3);

    float pcx = __fadd_rn(__fmul_rn(d0, widths),  ctr_x);
    float pcy = __fadd_rn(__fmul_rn(d1, heights), ctr_y);
    float pw  = __fmul_rn(expf(d2), widths);
    float ph  = __fmul_rn(expf(d3), heights);

    float hpw = __fmul_rn(0.5f, __fsub_rn(pw, 1.0f));
    float hph = __fmul_rn(0.5f, __fsub_rn(ph, 1.0f));
    float bx1 = __fsub_rn(pcx, hpw);
    float by1 = __fsub_rn(pcy, hph);
    float bx2 = __fadd_rn(pcx, hpw);
    float by2 = __fadd_rn(pcy, hph);

    float ow1 = __fsub_rn(ow, 1.0f), oh1 = __fsub_rn(oh, 1.0f);
    bx1 = fminf(fmaxf(bx1, 0.0f), ow1);
    by1 = fminf(fmaxf(by1, 0.0f), oh1);
    bx2 = fminf(fmaxf(bx2, 0.0f), ow1);
    by2 = fminf(fmaxf(by2, 0.0f), oh1);

    float s0 = cls[a * HW + hw];
    float s1 = cls[(A + a) * HW + hw];

    float wsv = __fadd_rn(__fsub_rn(bx2, bx1), 1.0f);
    float hsv = __fadd_rn(__fsub_rn(by2, by1), 1.0f);
    bool keep = (s1 > 0.2f) && ((wsv >= 6.16056f) || (hsv >= 6.16056f));
    float masked = keep ? s1 : -1e30f;

    boxes[m]  = make_float4(bx1, by1, bx2, by2);
    scores[m] = make_float2(s0, s1);

    int bucket = keep ? (1 + min(NBUCK - 2, max(0, (int)(s1 * (float)(NBUCK - 2))))) : 0;
    unsigned int fb = __float_as_uint(masked);
    fb = (fb & 0x80000000u) ? ~fb : (fb | 0x80000000u);
    keys[m] = ((unsigned long long)bucket << 51)
            | ((unsigned long long)fb << 15)
            | (unsigned long long)((~m) & 0x7fff);
}

// ---------------------------------------------------------------------------
// K2: single block, 1024 threads. LDS histogram over 8000 buckets ->
// wave-level suffix scan (2 barriers, was 20) -> threshold bucket B ->
// bucket-grouped compact into LDS (cap SCAP, global spill) -> rank =
// base[b] + tiny within-bucket compare -> scatter. (logic verified R8)
// ---------------------------------------------------------------------------
__global__ __launch_bounds__(1024) void k_mid(
    const unsigned long long* __restrict__ keys,
    const float4* __restrict__ boxes, const float2* __restrict__ scores,
    unsigned long long* __restrict__ skeys,
    float4* __restrict__ cboxes, float2* __restrict__ cscores,
    unsigned long long* __restrict__ kpm)
{
    __shared__ int s_base[NBUCK];               // counts -> suffix bases
    __shared__ int s_off[NBUCK];                // bucket fill offsets
    __shared__ unsigned long long s_keys[SCAP]; // compacted keys (LDS-resident)
    __shared__ unsigned long long s_kpm[NWORDS];
    __shared__ int s_wtot[16];
    __shared__ int s_B[1];

    const int t    = threadIdx.x;
    const int lane = t & 63;
    const int wv   = t >> 6;

    for (int k = t; k < NBUCK; k += 1024) { s_base[k] = 0; s_off[k] = 0; }
    if (t < NWORDS) s_kpm[t] = 0ull;
    __syncthreads();

    unsigned long long myk[17];
    #pragma unroll
    for (int q = 0; q < 17; ++q) {
        int i = q * 1024 + t;
        myk[q] = (i < N) ? keys[i] : 0ull;
        if (i < N) atomicAdd(&s_base[(int)(myk[q] >> 51)], 1);
    }
    __syncthreads();

    // per-thread group of 8 buckets; suffix scan via wave shuffles
    int c0=0,c1=0,c2=0,c3=0,c4=0,c5=0,c6=0,c7=0;
    int gsum = 0;
    const int g0 = t * 8;
    if (t < NBUCK / 8) {
        c0 = s_base[g0+0]; c1 = s_base[g0+1]; c2 = s_base[g0+2]; c3 = s_base[g0+3];
        c4 = s_base[g0+4]; c5 = s_base[g0+5]; c6 = s_base[g0+6]; c7 = s_base[g0+7];
        gsum = c0+c1+c2+c3+c4+c5+c6+c7;
    }
    int sfx = gsum;                       // within-wave inclusive suffix sum
    #pragma unroll
    for (int d = 1; d < 64; d <<= 1) {
        int v = __shfl_down(sfx, d, 64);
        if (lane + d < 64) sfx += v;
    }
    int wtot = __shfl(sfx, 0, 64);        // wave total
    if (lane == 0) s_wtot[wv] = wtot;
    __syncthreads();
    int later = 0;
    #pragma unroll
    for (int u = 0; u < 16; ++u) if (u > wv) later += s_wtot[u];
    int above = (sfx + later) - gsum;     // sum over threads > t

    if (t < NBUCK / 8) {
        int run = above;
        #define STEP(q, cq) { s_base[g0+q] = run; \
            if (run < MAX_CAND && run + cq >= MAX_CAND) s_B[0] = g0 + q; \
            run += cq; }
        STEP(7, c7) STEP(6, c6) STEP(5, c5) STEP(4, c4)
        STEP(3, c3) STEP(2, c2) STEP(1, c1) STEP(0, c0)
        #undef STEP
    }
    __syncthreads();
    const int B = s_B[0];

    // compact: bucket-grouped slots (higher buckets first); LDS up to SCAP
    #pragma unroll
    for (int q = 0; q < 17; ++q) {
        int i = q * 1024 + t;
        if (i < N) {
            int b = (int)(myk[q] >> 51);
            if (b >= B) {
                int slot = s_base[b] + atomicAdd(&s_off[b], 1);
                if (slot < SCAP) s_keys[slot] = myk[q];
                else             skeys[slot]  = myk[q];
            }
        }
    }
    __syncthreads();
    const int S = s_base[B] + s_off[B];

    // rank + scatter (within-bucket compare over ~2 members)
    for (int p = t; p < S; p += 1024) {
        unsigned long long k = (p < SCAP) ? s_keys[p] : skeys[p];
        int b  = (int)(k >> 51);
        int lo = s_base[b];
        int hi = lo + s_off[b];
        int cg = 0;
        for (int j = lo; j < hi; ++j) {
            unsigned long long kj = (j < SCAP) ? s_keys[j] : skeys[j];
            cg += (kj > k) ? 1 : 0;
        }
        int rank = lo + cg;
        if (rank < MAX_CAND) {
            int orig = ((int)k & 0x7fff) ^ 0x7fff;
            cboxes[rank]  = boxes[orig];
            cscores[rank] = scores[orig];
            if (b >= 1) atomicOr(&s_kpm[rank >> 6], 1ull << (rank & 63));
        }
    }
    __syncthreads();
    if (t < NWORDS) kpm[t] = s_kpm[t];
}

// ---------------------------------------------------------------------------
// K3: suppression bitmask, register-blocked + triangular + j-sliced,
// NO LDS: bi rows are wave-uniform loads (HW broadcast), bj rows are
// coalesced 1KB L2 reads. Zero LDS -> 2 blocks/CU, no staging barrier,
// kills 376 x 48KB redundant stagings (only ~450 of 3000 boxes used/block).
// ---------------------------------------------------------------------------
__device__ __forceinline__ bool iou_gt(
    float4 bi, float ai, float4 bj, float aj)
{
    float iw = fmaxf(__fsub_rn(fminf(bi.z, bj.z), fmaxf(bi.x, bj.x)), 0.0f);
    float ih = fmaxf(__fsub_rn(fminf(bi.w, bj.w), fmaxf(bi.y, bj.y)), 0.0f);
    float inter = __fmul_rn(iw, ih);
    float denom = fmaxf(__fsub_rn(__fadd_rn(ai, aj), inter), 1e-12f);
    return (inter / denom) > 0.7f;
}

__global__ __launch_bounds__(1024) void k_iou(
    const float4* __restrict__ cboxes, unsigned long long* __restrict__ sup)
{
    const int t    = threadIdx.x;
    const int lane = t & 63;
    const int wave = t >> 6;
    const int c = blockIdx.x;          // row chunk
    const int s = blockIdx.y;          // word slice
    const int r0 = c * 64 + wave * 4;

    float4 bi[4]; float ai[4];
    #pragma unroll
    for (int u = 0; u < 4; ++u) {
        int rc = min(r0 + u, MAX_CAND - 1);
        bi[u] = cboxes[rc];            // wave-uniform -> broadcast
        ai[u] = __fmul_rn(__fsub_rn(bi[u].z, bi[u].x), __fsub_rn(bi[u].w, bi[u].y));
    }

    for (int w = c + s; w < NWORDS; w += JSLICE) {
        int jc = w * 64 + lane;
        bool jv = (jc < MAX_CAND);
        float4 bj = cboxes[jv ? jc : (MAX_CAND - 1)];   // coalesced 1KB row
        float  aj = __fmul_rn(__fsub_rn(bj.z, bj.x), __fsub_rn(bj.w, bj.y));
        #pragma unroll
        for (int u = 0; u < 4; ++u) {
            int r = r0 + u;
            bool p = jv && (r < MAX_CAND) && (jc > r) && iou_gt(bi[u], ai[u], bj, aj);
            unsigned long long msk = __ballot(p);
            if (lane == 0 && r < MAX_CAND) sup[(size_t)r * NWORDS + w] = msk;
        }
    }
}

// ---------------------------------------------------------------------------
// K4: chunked greedy NMS over precomputed sup bits; early exit once kept>=300;
// nonzero-row skip; fixed-trip predicated fold; parallel output. (verified R3)
// ---------------------------------------------------------------------------
__global__ __launch_bounds__(1024) void k_nms_out(
    const unsigned long long* __restrict__ sup,
    const unsigned long long* __restrict__ kpm,
    const float4* __restrict__ cboxes, const float2* __restrict__ cscores,
    float* __restrict__ out)
{
    __shared__ unsigned long long buf[2][CHUNK_W];
    __shared__ unsigned long long kp[NWORDS + 1];
    __shared__ int sel[TOP_N];
    __shared__ int s_stop;

    int tid  = threadIdx.x;
    int lane = tid & 63;
    int wave = tid >> 6;

    for (int t = tid; t < TOP_N * 7; t += 1024) out[t] = 0.0f;
    for (int t = tid; t < TOP_N; t += 1024) sel[t] = -1;

    if (tid < NWORDS) kp[tid] = kpm[tid];

    {
        unsigned long long v0 = sup[tid];
        unsigned long long v1 = sup[tid + 1024];
        unsigned long long v2 = (tid + 2048 < CHUNK_W) ? sup[tid + 2048] : 0ull;
        buf[0][tid] = v0;
        buf[0][tid + 1024] = v1;
        if (tid + 2048 < CHUNK_W) buf[0][tid + 2048] = v2;
    }
    __syncthreads();

    int kept_total = 0;
    for (int w = 0; w < NWORDS; ++w) {
        int cur = w & 1;
        bool havnext = (w + 1 < NWORDS);

        unsigned long long v0 = 0, v1 = 0, v2 = 0;
        if (havnext) {
            const unsigned long long* src = sup + (size_t)(w + 1) * CHUNK_W;
            v0 = src[tid];
            v1 = src[tid + 1024];
            v2 = (tid + 2048 < CHUNK_W) ? src[tid + 2048] : 0ull;
        }

        if (wave == 0) {
            unsigned long long intra = buf[cur][lane * NWORDS + w];
            unsigned long long nz = __ballot(intra != 0ull);
            unsigned long long kw = kp[w];
            unsigned long long rem = kw & nz;
            while (rem) {
                int b = __ffsll((long long)rem) - 1;
                rem &= rem - 1;
                if ((kw >> b) & 1ull) {
                    unsigned long long row = __shfl(intra, b, 64);
                    kw  &= ~row;
                    rem &= ~row;
                }
            }
            if (lane == 0) kp[w] = kw;
            kept_total += __popcll(kw);
            bool stop = (kept_total >= TOP_N) || !havnext;
            if (lane == 0) s_stop = stop ? 1 : 0;

            if (!stop && lane < NWORDS && lane > w) {
                unsigned long long comb = 0;
                #pragma unroll 8
                for (int b = 0; b < 64; ++b) {
                    unsigned long long r = buf[cur][b * NWORDS + lane];
                    if ((kw >> b) & 1ull) comb |= r;
                }
                kp[lane] &= ~comb;
            }
        }

        if (havnext) {
            int nxt = cur ^ 1;
            buf[nxt][tid] = v0;
            buf[nxt][tid + 1024] = v1;
            if (tid + 2048 < CHUNK_W) buf[nxt][tid + 2048] = v2;
        }
        __syncthreads();
        if (s_stop) break;
    }

    if (wave == 0) {
        unsigned long long kw = (lane < NWORDS) ? kp[lane] : 0ull;
        int cnt = __popcll(kw);
        int pre = cnt;
        for (int d = 1; d < 64; d <<= 1) {
            int o = __shfl_up(pre, d, 64);
            if (lane >= d) pre += o;
        }
        int prefix = pre - cnt;
        while (kw && prefix < TOP_N) {
            int b = __ffsll((long long)kw) - 1;
            kw &= kw - 1;
            sel[prefix] = lane * 64 + b;
            prefix++;
        }
    }
    __syncthreads();

    if (tid < TOP_N) {
        int j = sel[tid];
        if (j >= 0) {
            float4 bx = cboxes[j];
            float2 sc = cscores[j];
            out[tid * 5 + 0] = 0.0f;
            out[tid * 5 + 1] = bx.x;
            out[tid * 5 + 2] = bx.y;
            out[tid * 5 + 3] = bx.z;
            out[tid * 5 + 4] = bx.w;
            out[TOP_N * 5 + tid * 2 + 0] = sc.x;
            out[TOP_N * 5 + tid * 2 + 1] = sc.y;
        }
    }
}

// ---------------------------------------------------------------------------
extern "C" void kernel_launch(void* const* d_in, const int* in_sizes, int n_in,
                              void* d_out, int out_size, void* d_ws, size_t ws_size,
                              hipStream_t stream) {
    const float* cls    = (const float*)d_in[0];
    const float* pred   = (const float*)d_in[1];
    const int*   iminfo = (const int*)d_in[2];
    float* out = (float*)d_out;

    char* p = (char*)d_ws;
    auto alloc = [&](size_t bytes) -> char* {
        char* q = p;
        p += (bytes + 255) & ~(size_t)255;
        return q;
    };
    float4* boxes  = (float4*)alloc((size_t)N * sizeof(float4));
    float2* scores = (float2*)alloc((size_t)N * sizeof(float2));
    unsigned long long* keys  = (unsigned long long*)alloc((size_t)N * 8);
    unsigned long long* skeys = (unsigned long long*)alloc((size_t)N * 8);
    float4* cboxes  = (float4*)alloc((size_t)MAX_CAND * sizeof(float4));
    float2* cscores = (float2*)alloc((size_t)MAX_CAND * sizeof(float2));
    unsigned long long* kpm = (unsigned long long*)alloc((size_t)NWORDS * 8);
    unsigned long long* sup = (unsigned long long*)alloc((size_t)MAX_CAND * NWORDS * 8);

    int nb = (N + 255) / 256;  // 68
    k_boxes <<<nb, 256, 0, stream>>>(cls, pred, iminfo, boxes, scores, keys);
    k_mid   <<<1, 1024, 0, stream>>>(keys, boxes, scores, skeys, cboxes, cscores, kpm);
    k_iou   <<<dim3(NWORDS, JSLICE), 1024, 0, stream>>>(cboxes, sup);
    k_nms_out<<<1, 1024, 0, stream>>>(sup, kpm, cboxes, cscores, out);
}

// Round 13
// 106.713 us; speedup vs baseline: 1.3486x; 1.0454x over previous
//
#include <hip/hip_runtime.h>
#include <stdint.h>

#define A 15
#define H_ 34
#define W_ 34
#define HW (H_*W_)
#define N (A*HW)            // 17340
#define MAX_CAND 3000
#define TOP_N 300
#define NWORDS 47           // ceil(3000/64)
#define CHUNK_W 3008        // 64 rows * 47 words per chunk
#define NBUCK 8000          // linear score buckets (monotone quantization)
#define JSLICE 8            // k_iou word-slices per chunk
#define SCAP 4224           // LDS-resident compacted keys cap (S typical ~3030)

__constant__ float c_aw[A] = {9.232984f, 16.0f, 27.712813f, 18.465969f, 32.0f, 55.425626f,
                              36.931937f, 64.0f, 110.851252f, 73.863875f, 128.0f, 221.702503f,
                              147.72775f, 256.0f, 443.405007f};
__constant__ float c_ah[A] = {27.72668f, 16.0f, 9.237604f, 55.453359f, 32.0f, 18.475209f,
                              110.906719f, 64.0f, 36.950417f, 221.813438f, 128.0f, 73.900834f,
                              443.626876f, 256.0f, 147.801669f};

// ---------------------------------------------------------------------------
// K1: decode boxes/scores; key = bucket(13) | score-bits(32) | ~idx(15).
// Exact reference op order; __f*_rn blocks FMA contraction. (verified R8)
// ---------------------------------------------------------------------------
__global__ __launch_bounds__(256) void k_boxes(
    const float* __restrict__ cls, const float* __restrict__ pred,
    const int* __restrict__ iminfo,
    float4* __restrict__ boxes, float2* __restrict__ scores,
    unsigned long long* __restrict__ keys)
{
    int m = blockIdx.x * 256 + threadIdx.x;
    if (m >= N) return;

    int a  = m % A;
    int hw = m / A;
    int w  = hw % W_;
    int h  = hw / W_;

    float ow = (float)iminfo[1];
    float oh = (float)iminfo[0];

    float aw = c_aw[a], ah = c_ah[a];
    float xm = __fmul_rn(-0.5f, __fsub_rn(aw, 1.0f));
    float ym = __fmul_rn(-0.5f, __fsub_rn(ah, 1.0f));
    float sxw = (float)(w * 8);
    float syh = (float)(h * 8);
    float x1 = __fadd_rn(sxw, xm);
    float y1 = __fadd_rn(syh, ym);
    float x2 = __fadd_rn(sxw, -xm);
    float y2 = __fadd_rn(syh, -ym);

    float widths  = __fadd_rn(__fsub_rn(x2, x1), 1.0f);
    float heights = __fadd_rn(__fsub_rn(y2, y1), 1.0f);
    float ctr_x = __fadd_rn(x1, __fmul_rn(0.5f, __fsub_rn(widths, 1.0f)));
    float ctr_y = __fadd_rn(y1, __fmul_rn(0.5f, __fsub_rn(heights, 1.0f)));

    const float std0 = 0.12677f,   std1 = 0.095741f, std2 = 0.3173f,    std3 = 0.281042f;
    const float mu0  = 0.000437f,  mu1  = 0.002586f, mu2  = -0.123953f, mu3  = -0.081469f;
    int pb = a * 4 * HW + hw;
    float d0 = __fadd_rn(__fmul_rn(pred[pb + 0 * HW], std0), mu0);
    float d1 = __fadd_rn(__fmul_rn(pred[pb + 1 * HW], std1), mu1);
    float d2 = __fadd_rn(__fmul_rn(pred[pb + 2 * HW], std2), mu2);
    float d3 = __fadd_rn(__fmul_rn(pred[pb + 3 * HW], std3), mu3);

    float pcx = __fadd_rn(__fmul_rn(d0, widths),  ctr_x);
    float pcy = __fadd_rn(__fmul_rn(d1, heights), ctr_y);
    float pw  = __fmul_rn(expf(d2), widths);
    float ph  = __fmul_rn(expf(d3), heights);

    float hpw = __fmul_rn(0.5f, __fsub_rn(pw, 1.0f));
    float hph = __fmul_rn(0.5f, __fsub_rn(ph, 1.0f));
    float bx1 = __fsub_rn(pcx, hpw);
    float by1 = __fsub_rn(pcy, hph);
    float bx2 = __fadd_rn(pcx, hpw);
    float by2 = __fadd_rn(pcy, hph);

    float ow1 = __fsub_rn(ow, 1.0f), oh1 = __fsub_rn(oh, 1.0f);
    bx1 = fminf(fmaxf(bx1, 0.0f), ow1);
    by1 = fminf(fmaxf(by1, 0.0f), oh1);
    bx2 = fminf(fmaxf(bx2, 0.0f), ow1);
    by2 = fminf(fmaxf(by2, 0.0f), oh1);

    float s0 = cls[a * HW + hw];
    float s1 = cls[(A + a) * HW + hw];

    float wsv = __fadd_rn(__fsub_rn(bx2, bx1), 1.0f);
    float hsv = __fadd_rn(__fsub_rn(by2, by1), 1.0f);
    bool keep = (s1 > 0.2f) && ((wsv >= 6.16056f) || (hsv >= 6.16056f));
    float masked = keep ? s1 : -1e30f;

    boxes[m]  = make_float4(bx1, by1, bx2, by2);
    scores[m] = make_float2(s0, s1);

    int bucket = keep ? (1 + min(NBUCK - 2, max(0, (int)(s1 * (float)(NBUCK - 2))))) : 0;
    unsigned int fb = __float_as_uint(masked);
    fb = (fb & 0x80000000u) ? ~fb : (fb | 0x80000000u);
    keys[m] = ((unsigned long long)bucket << 51)
            | ((unsigned long long)fb << 15)
            | (unsigned long long)((~m) & 0x7fff);
}

// ---------------------------------------------------------------------------
// K2: single block, 1024 threads. LDS histogram over 8000 buckets ->
// wave-level suffix scan -> threshold bucket B -> bucket-grouped compact into
// LDS (cap SCAP, global spill) -> rank = base[b] + within-bucket compare ->
// scatter. (verified R12)
// ---------------------------------------------------------------------------
__global__ __launch_bounds__(1024) void k_mid(
    const unsigned long long* __restrict__ keys,
    const float4* __restrict__ boxes, const float2* __restrict__ scores,
    unsigned long long* __restrict__ skeys,
    float4* __restrict__ cboxes, float2* __restrict__ cscores,
    unsigned long long* __restrict__ kpm)
{
    __shared__ int s_base[NBUCK];               // counts -> suffix bases
    __shared__ int s_off[NBUCK];                // bucket fill offsets
    __shared__ unsigned long long s_keys[SCAP]; // compacted keys (LDS-resident)
    __shared__ unsigned long long s_kpm[NWORDS];
    __shared__ int s_wtot[16];
    __shared__ int s_B[1];

    const int t    = threadIdx.x;
    const int lane = t & 63;
    const int wv   = t >> 6;

    for (int k = t; k < NBUCK; k += 1024) { s_base[k] = 0; s_off[k] = 0; }
    if (t < NWORDS) s_kpm[t] = 0ull;
    __syncthreads();

    unsigned long long myk[17];
    #pragma unroll
    for (int q = 0; q < 17; ++q) {
        int i = q * 1024 + t;
        myk[q] = (i < N) ? keys[i] : 0ull;
        if (i < N) atomicAdd(&s_base[(int)(myk[q] >> 51)], 1);
    }
    __syncthreads();

    int c0=0,c1=0,c2=0,c3=0,c4=0,c5=0,c6=0,c7=0;
    int gsum = 0;
    const int g0 = t * 8;
    if (t < NBUCK / 8) {
        c0 = s_base[g0+0]; c1 = s_base[g0+1]; c2 = s_base[g0+2]; c3 = s_base[g0+3];
        c4 = s_base[g0+4]; c5 = s_base[g0+5]; c6 = s_base[g0+6]; c7 = s_base[g0+7];
        gsum = c0+c1+c2+c3+c4+c5+c6+c7;
    }
    int sfx = gsum;                       // within-wave inclusive suffix sum
    #pragma unroll
    for (int d = 1; d < 64; d <<= 1) {
        int v = __shfl_down(sfx, d, 64);
        if (lane + d < 64) sfx += v;
    }
    int wtot = __shfl(sfx, 0, 64);        // wave total
    if (lane == 0) s_wtot[wv] = wtot;
    __syncthreads();
    int later = 0;
    #pragma unroll
    for (int u = 0; u < 16; ++u) if (u > wv) later += s_wtot[u];
    int above = (sfx + later) - gsum;     // sum over threads > t

    if (t < NBUCK / 8) {
        int run = above;
        #define STEP(q, cq) { s_base[g0+q] = run; \
            if (run < MAX_CAND && run + cq >= MAX_CAND) s_B[0] = g0 + q; \
            run += cq; }
        STEP(7, c7) STEP(6, c6) STEP(5, c5) STEP(4, c4)
        STEP(3, c3) STEP(2, c2) STEP(1, c1) STEP(0, c0)
        #undef STEP
    }
    __syncthreads();
    const int B = s_B[0];

    #pragma unroll
    for (int q = 0; q < 17; ++q) {
        int i = q * 1024 + t;
        if (i < N) {
            int b = (int)(myk[q] >> 51);
            if (b >= B) {
                int slot = s_base[b] + atomicAdd(&s_off[b], 1);
                if (slot < SCAP) s_keys[slot] = myk[q];
                else             skeys[slot]  = myk[q];
            }
        }
    }
    __syncthreads();
    const int S = s_base[B] + s_off[B];

    for (int p = t; p < S; p += 1024) {
        unsigned long long k = (p < SCAP) ? s_keys[p] : skeys[p];
        int b  = (int)(k >> 51);
        int lo = s_base[b];
        int hi = lo + s_off[b];
        int cg = 0;
        for (int j = lo; j < hi; ++j) {
            unsigned long long kj = (j < SCAP) ? s_keys[j] : skeys[j];
            cg += (kj > k) ? 1 : 0;
        }
        int rank = lo + cg;
        if (rank < MAX_CAND) {
            int orig = ((int)k & 0x7fff) ^ 0x7fff;
            cboxes[rank]  = boxes[orig];
            cscores[rank] = scores[orig];
            if (b >= 1) atomicOr(&s_kpm[rank >> 6], 1ull << (rank & 63));
        }
    }
    __syncthreads();
    if (t < NWORDS) kpm[t] = s_kpm[t];
}

// ---------------------------------------------------------------------------
// K3: suppression bitmask, register-blocked + triangular + j-sliced, no LDS.
// (verified R12)
// ---------------------------------------------------------------------------
__device__ __forceinline__ bool iou_gt(
    float4 bi, float ai, float4 bj, float aj)
{
    float iw = fmaxf(__fsub_rn(fminf(bi.z, bj.z), fmaxf(bi.x, bj.x)), 0.0f);
    float ih = fmaxf(__fsub_rn(fminf(bi.w, bj.w), fmaxf(bi.y, bj.y)), 0.0f);
    float inter = __fmul_rn(iw, ih);
    float denom = fmaxf(__fsub_rn(__fadd_rn(ai, aj), inter), 1e-12f);
    return (inter / denom) > 0.7f;
}

__global__ __launch_bounds__(1024) void k_iou(
    const float4* __restrict__ cboxes, unsigned long long* __restrict__ sup)
{
    const int t    = threadIdx.x;
    const int lane = t & 63;
    const int wave = t >> 6;
    const int c = blockIdx.x;          // row chunk
    const int s = blockIdx.y;          // word slice
    const int r0 = c * 64 + wave * 4;

    float4 bi[4]; float ai[4];
    #pragma unroll
    for (int u = 0; u < 4; ++u) {
        int rc = min(r0 + u, MAX_CAND - 1);
        bi[u] = cboxes[rc];            // wave-uniform -> broadcast
        ai[u] = __fmul_rn(__fsub_rn(bi[u].z, bi[u].x), __fsub_rn(bi[u].w, bi[u].y));
    }

    for (int w = c + s; w < NWORDS; w += JSLICE) {
        int jc = w * 64 + lane;
        bool jv = (jc < MAX_CAND);
        float4 bj = cboxes[jv ? jc : (MAX_CAND - 1)];   // coalesced 1KB row
        float  aj = __fmul_rn(__fsub_rn(bj.z, bj.x), __fsub_rn(bj.w, bj.y));
        #pragma unroll
        for (int u = 0; u < 4; ++u) {
            int r = r0 + u;
            bool p = jv && (r < MAX_CAND) && (jc > r) && iou_gt(bi[u], ai[u], bj, aj);
            unsigned long long msk = __ballot(p);
            if (lane == 0 && r < MAX_CAND) sup[(size_t)r * NWORDS + w] = msk;
        }
    }
}

// ---------------------------------------------------------------------------
// K4: chunked greedy NMS; early exit once kept>=300; nonzero-row skip in the
// serial resolve (wave0); NEW: fold parallelized over all 16 waves -- per
// target word, lane b reads row b's word (1 LDS read) and a 6-step shfl_xor
// OR-butterfly combines across lanes (was: wave0 only, 64 serialized reads
// per target lane). Costs one extra barrier/chunk to publish kw.
// ---------------------------------------------------------------------------
__global__ __launch_bounds__(1024) void k_nms_out(
    const unsigned long long* __restrict__ sup,
    const unsigned long long* __restrict__ kpm,
    const float4* __restrict__ cboxes, const float2* __restrict__ cscores,
    float* __restrict__ out)
{
    __shared__ unsigned long long buf[2][CHUNK_W];
    __shared__ unsigned long long kp[NWORDS + 1];
    __shared__ unsigned long long s_kw;
    __shared__ int sel[TOP_N];
    __shared__ int s_stop;

    int tid  = threadIdx.x;
    int lane = tid & 63;
    int wave = tid >> 6;

    for (int t = tid; t < TOP_N * 7; t += 1024) out[t] = 0.0f;
    for (int t = tid; t < TOP_N; t += 1024) sel[t] = -1;

    if (tid < NWORDS) kp[tid] = kpm[tid];

    {
        unsigned long long v0 = sup[tid];
        unsigned long long v1 = sup[tid + 1024];
        unsigned long long v2 = (tid + 2048 < CHUNK_W) ? sup[tid + 2048] : 0ull;
        buf[0][tid] = v0;
        buf[0][tid + 1024] = v1;
        if (tid + 2048 < CHUNK_W) buf[0][tid + 2048] = v2;
    }
    __syncthreads();

    int kept_total = 0;   // meaningful in wave0 only (stop decided there)
    for (int w = 0; w < NWORDS; ++w) {
        int cur = w & 1;
        bool havnext = (w + 1 < NWORDS);

        // issue next chunk's global loads EARLY (hide under resolve+fold)
        unsigned long long v0 = 0, v1 = 0, v2 = 0;
        if (havnext) {
            const unsigned long long* src = sup + (size_t)(w + 1) * CHUNK_W;
            v0 = src[tid];
            v1 = src[tid + 1024];
            v2 = (tid + 2048 < CHUNK_W) ? src[tid + 2048] : 0ull;
        }

        // ---- serial resolve (wave 0), ffs-skip over nonzero survivor rows
        if (wave == 0) {
            unsigned long long intra = buf[cur][lane * NWORDS + w];
            unsigned long long nz = __ballot(intra != 0ull);
            unsigned long long kw = kp[w];
            unsigned long long rem = kw & nz;
            while (rem) {
                int b = __ffsll((long long)rem) - 1;
                rem &= rem - 1;
                if ((kw >> b) & 1ull) {
                    unsigned long long row = __shfl(intra, b, 64);
                    kw  &= ~row;
                    rem &= ~row;
                }
            }
            kept_total += __popcll(kw);
            bool stop = (kept_total >= TOP_N) || !havnext;
            if (lane == 0) {
                kp[w] = kw;
                s_kw  = kw;
                s_stop = stop ? 1 : 0;
            }
        }
        __syncthreads();   // publish s_kw / s_stop; cur buffer stable

        // ---- fold: all 16 waves, strided target words; OR-butterfly
        if (!s_stop) {
            unsigned long long kwf = s_kw;
            bool mybit = (kwf >> lane) & 1ull;
            for (int u = w + 1 + wave; u < NWORDS; u += 16) {
                unsigned long long r = buf[cur][lane * NWORDS + u];
                unsigned long long m = mybit ? r : 0ull;
                #pragma unroll
                for (int d = 1; d < 64; d <<= 1) m |= __shfl_xor(m, d, 64);
                if (lane == 0) kp[u] &= ~m;
            }
        }

        // ---- complete staged copy into the other buffer
        if (havnext) {
            int nxt = cur ^ 1;
            buf[nxt][tid] = v0;
            buf[nxt][tid + 1024] = v1;
            if (tid + 2048 < CHUNK_W) buf[nxt][tid + 2048] = v2;
        }
        __syncthreads();
        if (s_stop) break;
    }

    if (wave == 0) {
        unsigned long long kw = (lane < NWORDS) ? kp[lane] : 0ull;
        int cnt = __popcll(kw);
        int pre = cnt;
        for (int d = 1; d < 64; d <<= 1) {
            int o = __shfl_up(pre, d, 64);
            if (lane >= d) pre += o;
        }
        int prefix = pre - cnt;
        while (kw && prefix < TOP_N) {
            int b = __ffsll((long long)kw) - 1;
            kw &= kw - 1;
            sel[prefix] = lane * 64 + b;
            prefix++;
        }
    }
    __syncthreads();

    if (tid < TOP_N) {
        int j = sel[tid];
        if (j >= 0) {
            float4 bx = cboxes[j];
            float2 sc = cscores[j];
            out[tid * 5 + 0] = 0.0f;
            out[tid * 5 + 1] = bx.x;
            out[tid * 5 + 2] = bx.y;
            out[tid * 5 + 3] = bx.z;
            out[tid * 5 + 4] = bx.w;
            out[TOP_N * 5 + tid * 2 + 0] = sc.x;
            out[TOP_N * 5 + tid * 2 + 1] = sc.y;
        }
    }
}

// ---------------------------------------------------------------------------
extern "C" void kernel_launch(void* const* d_in, const int* in_sizes, int n_in,
                              void* d_out, int out_size, void* d_ws, size_t ws_size,
                              hipStream_t stream) {
    const float* cls    = (const float*)d_in[0];
    const float* pred   = (const float*)d_in[1];
    const int*   iminfo = (const int*)d_in[2];
    float* out = (float*)d_out;

    char* p = (char*)d_ws;
    auto alloc = [&](size_t bytes) -> char* {
        char* q = p;
        p += (bytes + 255) & ~(size_t)255;
        return q;
    };
    float4* boxes  = (float4*)alloc((size_t)N * sizeof(float4));
    float2* scores = (float2*)alloc((size_t)N * sizeof(float2));
    unsigned long long* keys  = (unsigned long long*)alloc((size_t)N * 8);
    unsigned long long* skeys = (unsigned long long*)alloc((size_t)N * 8);
    float4* cboxes  = (float4*)alloc((size_t)MAX_CAND * sizeof(float4));
    float2* cscores = (float2*)alloc((size_t)MAX_CAND * sizeof(float2));
    unsigned long long* kpm = (unsigned long long*)alloc((size_t)NWORDS * 8);
    unsigned long long* sup = (unsigned long long*)alloc((size_t)MAX_CAND * NWORDS * 8);

    int nb = (N + 255) / 256;  // 68
    k_boxes <<<nb, 256, 0, stream>>>(cls, pred, iminfo, boxes, scores, keys);
    k_mid   <<<1, 1024, 0, stream>>>(keys, boxes, scores, skeys, cboxes, cscores, kpm);
    k_iou   <<<dim3(NWORDS, JSLICE), 1024, 0, stream>>>(cboxes, sup);
    k_nms_out<<<1, 1024, 0, stream>>>(sup, kpm, cboxes, cscores, out);
}